// Round 10
// baseline (338.906 us; speedup 1.0000x reference)
//
#include <hip/hip_runtime.h>
#include <stdint.h>

#define GD 128
#define H1 128
#define H2 128
#define NBASES 32
#define NREL 8
#define KA 1152   // logical K = 8*128 (relation means) + 128 (x | root)

typedef __attribute__((ext_vector_type(8))) short bf16x8;
typedef __attribute__((ext_vector_type(4))) float f32x4;

static inline size_t align256(size_t x){ return (x + 255) & ~(size_t)255; }

__device__ __forceinline__ float bf2f(uint32_t u16){
  union { uint32_t u; float f; } c; c.u = (u16 & 0xffffu) << 16; return c.f;
}
__device__ __forceinline__ unsigned short f2bf(float f){
  union { float f; uint32_t u; } c; c.f = f;
  uint32_t u = c.u;
  u += 0x7fffu + ((u >> 16) & 1u);   // RTNE (finite inputs)
  return (unsigned short)(u >> 16);
}
__device__ __forceinline__ uint32_t pkbf(float a, float b){
  union { float f; uint32_t u; } ca, cb; ca.f = a; cb.f = b;
  return __builtin_amdgcn_perm(cb.u + 0x8000u, ca.u + 0x8000u, 0x07060302u);
}

__device__ __forceinline__ void async_copy16(void* lds_dst, const void* gsrc){
  __builtin_amdgcn_global_load_lds(
      (const __attribute__((address_space(1))) uint32_t*)gsrc,
      (__attribute__((address_space(3))) uint32_t*)lds_dst, 16, 0, 0);
}

// ==== merged prep: Bht build (coalesced) | B2t build (log2e prescale) | x cast | xbf pad zero | hist ====
__global__ void k_prep(const float* __restrict__ comp, const float* __restrict__ basis,
                       const float* __restrict__ root, unsigned short* __restrict__ Bht,
                       const float* __restrict__ wk, const float* __restrict__ wq,
                       const float* __restrict__ wv, const float* __restrict__ wsk,
                       const float* __restrict__ bk, const float* __restrict__ bq,
                       const float* __restrict__ bv, const float* __restrict__ bs,
                       unsigned short* __restrict__ B2t, float* __restrict__ Bb,
                       const float4* __restrict__ x, uint2* __restrict__ xout, int cnt4,
                       uint32_t* __restrict__ xpadz, int npadz,
                       const int* __restrict__ edst, const int* __restrict__ etyp,
                       int* __restrict__ cnt, int E, int n){
  const float LOG2E = 1.4426950408889634f;
  int b = blockIdx.x, t = threadIdx.x;
  if (b < 128){
    // block = K-row i; lane = output col o (coalesced basis reads, 256B/wave segments)
    int i = b;
    int o = t & 127, rh = t >> 7;
    float bv[NBASES];
    #pragma unroll
    for (int bb = 0; bb < NBASES; ++bb)
      bv[bb] = basis[((size_t)bb*GD + i)*H1 + o];
    #pragma unroll
    for (int rr = 0; rr < 4; ++rr){
      int r = rh*4 + rr;
      float acc = 0.f;
      #pragma unroll
      for (int bb = 0; bb < NBASES; ++bb)
        acc += comp[r*NBASES + bb] * bv[bb];
      Bht[(size_t)o*KA + r*128 + i] = f2bf(acc);
    }
    if (rh == 1) Bht[(size_t)o*KA + 1024 + i] = f2bf(root[(size_t)i*H1 + o]);
  } else if (b < 128 + 256){
    int idx = (b - 128)*256 + t;         // < 65536 = 512*H1
    int c = idx / H1, k = idx % H1;
    const float* w = (c < 128) ? wk : (c < 256) ? wq : (c < 384) ? wv : wsk;
    float val = w[(size_t)k*H2 + (c & 127)];
    if (c < 256) val *= LOG2E;           // fold log2e into k,q so edge2 uses raw v_exp
    B2t[idx] = f2bf(val);
    if (idx < 512){
      const float* bia = (idx < 128) ? bk : (idx < 256) ? bq : (idx < 384) ? bv : bs;
      float bval = bia[idx & 127];
      if (idx < 256) bval *= LOG2E;
      Bb[idx] = bval;
    }
  } else {
    int cb = b - (128 + 256);
    int ncastb = (cnt4 + 1023) >> 10;
    if (cb < ncastb){
      int base = cb*1024 + t;
      #pragma unroll
      for (int u = 0; u < 4; ++u){
        int i = base + u*256;
        if (i < cnt4){
          float4 v = x[i];
          uint2 o; o.x = pkbf(v.x, v.y); o.y = pkbf(v.z, v.w);
          xout[i] = o;
        }
      }
    } else if (cb < ncastb + 12){
      int i = (cb - ncastb)*256 + t;
      if (i < npadz) xpadz[i] = 0u;      // zero xbf pad rows (hqkv root chunk reads them)
    } else {
      int e = (cb - ncastb - 12)*256 + t;
      if (e < E) atomicAdd(&cnt[etyp[e]*n + edst[e]], 1);
    }
  }
}

// ---- parallel scan, stage A ----
__global__ void k_scanA(const int* __restrict__ deg, int* __restrict__ off,
                        int* __restrict__ btot, int len){
  __shared__ int wsum[16];
  int t = threadIdx.x, lane = t & 63, w = t >> 6;
  int i0 = blockIdx.x*8192 + t*8;
  int v[8];
  if (i0 + 7 < len){
    int4 va = *(const int4*)(deg + i0);
    int4 vb = *(const int4*)(deg + i0 + 4);
    v[0]=va.x; v[1]=va.y; v[2]=va.z; v[3]=va.w;
    v[4]=vb.x; v[5]=vb.y; v[6]=vb.z; v[7]=vb.w;
  } else {
    #pragma unroll
    for (int u = 0; u < 8; ++u) v[u] = (i0+u < len) ? deg[i0+u] : 0;
  }
  int s[8]; s[0] = v[0];
  #pragma unroll
  for (int u = 1; u < 8; ++u) s[u] = s[u-1] + v[u];
  int x = s[7];
  #pragma unroll
  for (int d = 1; d < 64; d <<= 1){
    int u = __shfl_up(x, d, 64);
    if (lane >= d) x += u;
  }
  if (lane == 63) wsum[w] = x;
  __syncthreads();
  if (t < 16){
    int y = wsum[t];
    #pragma unroll
    for (int d = 1; d < 16; d <<= 1){
      int u = __shfl_up(y, d, 16);
      if (t >= d) y += u;
    }
    wsum[t] = y;
  }
  __syncthreads();
  int woff = (w > 0) ? wsum[w-1] : 0;
  int excl = woff + x - s[7];
  #pragma unroll
  for (int u = 0; u < 8; ++u)
    if (i0+u < len) off[i0+u] = excl + s[u] - v[u];
  if (t == 0) btot[blockIdx.x] = wsum[15];
}

// ---- scan stage B ----
__global__ void k_scanB(const int* __restrict__ btot, int* __restrict__ off,
                        int* __restrict__ cursor, int len, int sentinel){
  int t = threadIdx.x, bid = blockIdx.x;
  int add = 0;
  for (int j = 0; j < bid; ++j) add += btot[j];
  int i0 = bid*8192 + t*8;
  #pragma unroll
  for (int u = 0; u < 8; ++u){
    int i = i0 + u;
    if (i < len){ int val = off[i] + add; off[i] = val; cursor[i] = val; }
  }
  if (bid == 0 && t == 0) off[len] = sentinel;
}

// pk[pos] = src, (r,dst)-sorted
__global__ void k_scatter_rd(const int* __restrict__ src, const int* __restrict__ dst,
                             const int* __restrict__ typ, int* __restrict__ cursor,
                             int* __restrict__ pk, int E, int n){
  int e = blockIdx.x*blockDim.x + threadIdx.x;
  if (e >= E) return;
  int pos = atomicAdd(&cursor[typ[e]*n + dst[e]], 1);
  pk[pos] = src[e];
}

// ---- one wave per dst node: A2[d] = [mean_r(x_src) for r=0..7] (bf16, width 1024) ----
// merged-relation pipelined gather: batched 8 across relation boundaries,
// scalar-uniform flush when the (sorted) relation id changes. Zero barriers, max occupancy.
__global__ void k_agg(const int* __restrict__ off_rd, const int* __restrict__ pk_rd,
                      const uint32_t* __restrict__ x32, unsigned short* __restrict__ A2,
                      int n, int npad){
  int wid = blockIdx.x*(blockDim.x >> 6) + (threadIdx.x >> 6);
  int lane = threadIdx.x & 63;
  if (wid >= npad) return;
  uint32_t* arow = (uint32_t*)(A2 + (size_t)wid*1024);
  if (wid >= n){
    #pragma unroll
    for (int u = 0; u < 8; ++u) arow[u*64 + lane] = 0u;
    return;
  }
  int r8 = lane & 7;
  int o_r = off_rd[(size_t)r8*n + wid];
  int e_r = off_rd[(size_t)r8*n + wid + 1];
  int c_r = e_r - o_r;
  float ic_r = (c_r > 0) ? __builtin_amdgcn_rcpf((float)c_r) : 0.f;
  int c0_ = __builtin_amdgcn_readlane(c_r, 0), c1_ = __builtin_amdgcn_readlane(c_r, 1);
  int c2_ = __builtin_amdgcn_readlane(c_r, 2), c3_ = __builtin_amdgcn_readlane(c_r, 3);
  int c4_ = __builtin_amdgcn_readlane(c_r, 4), c5_ = __builtin_amdgcn_readlane(c_r, 5);
  int c6_ = __builtin_amdgcn_readlane(c_r, 6), c7_ = __builtin_amdgcn_readlane(c_r, 7);
  int o0_ = __builtin_amdgcn_readlane(o_r, 0), o1_ = __builtin_amdgcn_readlane(o_r, 1);
  int o2_ = __builtin_amdgcn_readlane(o_r, 2), o3_ = __builtin_amdgcn_readlane(o_r, 3);
  int o4_ = __builtin_amdgcn_readlane(o_r, 4), o5_ = __builtin_amdgcn_readlane(o_r, 5);
  int o6_ = __builtin_amdgcn_readlane(o_r, 6), o7_ = __builtin_amdgcn_readlane(o_r, 7);
  int p1 = c0_, p2 = p1 + c1_, p3 = p2 + c2_, p4 = p3 + c3_;
  int p5 = p4 + c4_, p6 = p5 + c5_, p7 = p6 + c6_, dg = p7 + c7_;

  int cr = 0;                 // relation currently being accumulated (edges are rel-sorted)
  float a0 = 0.f, a1 = 0.f;

#define FLUSH(RK)                                                               \
  {                                                                             \
    float ic = __int_as_float(__builtin_amdgcn_readlane(__float_as_int(ic_r), cr)); \
    arow[cr*64 + lane] = pkbf(a0*ic, a1*ic);                                    \
    for (int q = cr + 1; q < (RK); ++q) arow[q*64 + lane] = 0u;                 \
    cr = (RK); a0 = 0.f; a1 = 0.f;                                              \
  }

  for (int jb = 0; jb < dg; jb += 64){
    int i = jb + lane;
    int adj = o0_, rel = 0;
    adj = (i >= p1) ? (o1_ - p1) : adj;  rel += (i >= p1);
    adj = (i >= p2) ? (o2_ - p2) : adj;  rel += (i >= p2);
    adj = (i >= p3) ? (o3_ - p3) : adj;  rel += (i >= p3);
    adj = (i >= p4) ? (o4_ - p4) : adj;  rel += (i >= p4);
    adj = (i >= p5) ? (o5_ - p5) : adj;  rel += (i >= p5);
    adj = (i >= p6) ? (o6_ - p6) : adj;  rel += (i >= p6);
    adj = (i >= p7) ? (o7_ - p7) : adj;  rel += (i >= p7);
    int m = dg - jb; if (m > 64) m = 64;
    int pj = (lane < m) ? pk_rd[adj + i] : 0;
    int jj = 0;
    for (; jj + 8 <= m; jj += 8){
      uint32_t g[8];
      #pragma unroll
      for (int k = 0; k < 8; ++k){
        int sN = __builtin_amdgcn_readlane(pj, jj + k);
        g[k] = x32[(size_t)(uint32_t)sN*64 + lane];
      }
      #pragma unroll
      for (int k = 0; k < 8; ++k){
        int rk = __builtin_amdgcn_readlane(rel, jj + k);
        if (rk != cr) FLUSH(rk);
        a0 += bf2f(g[k]); a1 += bf2f(g[k] >> 16);
      }
    }
    for (; jj < m; jj += 4){             // padded batch-4 tail: keeps 4 loads in flight
      int lim = m - 1;
      uint32_t g[4];
      #pragma unroll
      for (int k = 0; k < 4; ++k){
        int tt = jj + k; if (tt > lim) tt = lim;
        int sN = __builtin_amdgcn_readlane(pj, tt);
        g[k] = x32[(size_t)(uint32_t)sN*64 + lane];
      }
      #pragma unroll
      for (int k = 0; k < 4; ++k){
        int tt = jj + k;
        if (tt < m){
          int rk = __builtin_amdgcn_readlane(rel, tt);
          if (rk != cr) FLUSH(rk);
          a0 += bf2f(g[k]); a1 += bf2f(g[k] >> 16);
        }
      }
    }
  }
  FLUSH(8)                               // write last accumulated rel + trailing zeros
#undef FLUSH
}

// ---- fused hgemm+gemm2 (k_hqkv), 64-row tiles (782 blocks):
//      GEMM1: h_tile[64][128] = [A2|xbf] @ Bht^T + bias1, kept in LDS (bf16, XOR-swizzled);
//      GEMM2: per 128-col chunk c0: h_tile @ B2t[c0]^T + Bb -> kqv/skipb (transpose epilogue).
//      h never touches global memory.
__launch_bounds__(256)
__global__ void k_hqkv(const unsigned short* __restrict__ A, const unsigned short* __restrict__ xb,
                       const unsigned short* __restrict__ Bt,   // Bht [128][1152]
                       const unsigned short* __restrict__ B2,   // B2t [512][128]
                       const float* __restrict__ bias1, const float* __restrict__ Bb,
                       unsigned short* __restrict__ kqv, unsigned short* __restrict__ skipb){
  __shared__ char lds[45568];   // [0,4K): A-stage; [4K,12K): B-stage; [12K,28K): h-tile; [28K,44.5K): epilogue
  int t = threadIdx.x, lane = t & 63, wave = t >> 6;
  int row0 = blockIdx.x * 64;
  int mrow = lane & 15, quad = lane >> 4;
  int s = (mrow >> 1) & 3;
  int colsw = (((t & 3) ^ ((t >> 3) & 3)) << 3);

  const unsigned short* Asrc = A  + (size_t)(row0 + (t >> 2))*1024 + colsw;
  const unsigned short* Xsrc = xb + (size_t)(row0 + (t >> 2))*GD   + colsw;
  const unsigned short* Bsrc = Bt + (size_t)(t >> 2)*KA + colsw;
  char* ldsB  = lds + 4096;
  char* htile = lds + 12288;
  char* eb    = lds + 28672;

  int aoff = mrow*64 + ((quad ^ s) << 4);                     // + i*1024
  int boff = 4096 + (wave*32 + mrow)*64 + ((quad ^ s) << 4);  // + j*1024
  int axor = (mrow & 7) << 4;

  f32x4 acc[4][2];
  #pragma unroll
  for (int i = 0; i < 4; ++i)
    #pragma unroll
    for (int j = 0; j < 2; ++j) acc[i][j] = (f32x4){0.f,0.f,0.f,0.f};

  // ---- GEMM1: K = 1152 (A2 cols 0..1023, then xbf as cols 1024..1151) ----
  for (int kt = 0; kt < KA; kt += 32){
    const unsigned short* ap = (kt < 1024) ? (Asrc + kt) : (Xsrc + (kt - 1024));
    __syncthreads();
    async_copy16(lds  + wave*1024, ap);                        // A rows 0-63 (4KB)
    async_copy16(ldsB + wave*1024, Bsrc + kt);                 // B rows 0-63
    async_copy16(ldsB + 4096 + wave*1024, Bsrc + (size_t)64*KA + kt);  // B rows 64-127
    __syncthreads();
    bf16x8 af[4], bf[2];
    #pragma unroll
    for (int i = 0; i < 4; ++i) af[i] = *(const bf16x8*)(lds + aoff + i*1024);
    #pragma unroll
    for (int j = 0; j < 2; ++j) bf[j] = *(const bf16x8*)(lds + boff + j*1024);
    #pragma unroll
    for (int i = 0; i < 4; ++i)
      #pragma unroll
      for (int j = 0; j < 2; ++j)
        acc[i][j] = __builtin_amdgcn_mfma_f32_16x16x32_bf16(af[i], bf[j], acc[i][j], 0, 0, 0);
  }
  // ---- h-tile to LDS (bias + bf16, 256B rows, 16B-block XOR swizzle) ----
  {
    float bc1[2];
    #pragma unroll
    for (int j = 0; j < 2; ++j) bc1[j] = bias1[wave*32 + j*16 + mrow];
    #pragma unroll
    for (int j = 0; j < 2; ++j){
      int col = wave*32 + j*16 + mrow;
      #pragma unroll
      for (int i = 0; i < 4; ++i)
        #pragma unroll
        for (int rg = 0; rg < 4; ++rg){
          int row = i*16 + quad*4 + rg;
          *(unsigned short*)(htile + row*256 + ((col*2) ^ ((row & 7) << 4)))
              = f2bf(acc[i][j][rg] + bc1[j]);
        }
    }
  }
  __syncthreads();   // h-tile visible

  // ---- GEMM2: 4 chunks of 128 output cols ----
  for (int c0 = 0; c0 < 4; ++c0){
    #pragma unroll
    for (int i = 0; i < 4; ++i)
      #pragma unroll
      for (int j = 0; j < 2; ++j) acc[i][j] = (f32x4){0.f,0.f,0.f,0.f};
    const unsigned short* B2src = B2 + (size_t)(c0*128 + (t >> 2))*H1 + colsw;
    for (int kt = 0; kt < 128; kt += 32){
      __syncthreads();
      async_copy16(ldsB + wave*1024, B2src + kt);
      async_copy16(ldsB + 4096 + wave*1024, B2src + (size_t)64*H1 + kt);
      __syncthreads();
      bf16x8 af[4], bf[2];
      #pragma unroll
      for (int i = 0; i < 4; ++i)
        af[i] = *(const bf16x8*)(htile + (i*16 + mrow)*256 + (((kt + quad*8)*2) ^ axor));
      #pragma unroll
      for (int j = 0; j < 2; ++j) bf[j] = *(const bf16x8*)(lds + boff + j*1024);
      #pragma unroll
      for (int i = 0; i < 4; ++i)
        #pragma unroll
        for (int j = 0; j < 2; ++j)
          acc[i][j] = __builtin_amdgcn_mfma_f32_16x16x32_bf16(af[i], bf[j], acc[i][j], 0, 0, 0);
    }
    // epilogue: bias + bf16 -> transpose buffer -> coalesced stores
    float bc2[2];
    #pragma unroll
    for (int j = 0; j < 2; ++j) bc2[j] = Bb[c0*128 + wave*32 + j*16 + mrow];
    #pragma unroll
    for (int j = 0; j < 2; ++j){
      int col = wave*32 + j*16 + mrow;
      #pragma unroll
      for (int i = 0; i < 4; ++i)
        #pragma unroll
        for (int rg = 0; rg < 4; ++rg){
          int rl = i*16 + quad*4 + rg;
          *(unsigned short*)(eb + rl*264 + col*2) = f2bf(acc[i][j][rg] + bc2[j]);
        }
    }
    __syncthreads();
    uint32_t vv[16];
    #pragma unroll
    for (int u = 0; u < 8; ++u)
      *(uint2*)&vv[u*2] = *(const uint2*)(eb + lane*264 + wave*64 + u*8);
    unsigned short* dstb; size_t ldu;
    if (c0 < 3){ dstb = kqv + c0*128; ldu = 384; } else { dstb = skipb; ldu = 128; }
    unsigned short* gp = dstb + (size_t)(row0 + lane)*ldu + wave*32;
    #pragma unroll
    for (int u = 0; u < 4; ++u)
      *(uint4*)(gp + u*8) = *(const uint4*)&vv[u*4];
    __syncthreads();   // eb reads done before next chunk's epilogue writes
  }
}

// ---- one wave per dst node: out = sum_e sigmoid(k+q)*v + skip (pure write) ----
// kqv layout: [row][k(128)|q(128)|v(128)]; k,q prescaled by log2e: sigmoid = rcp(1+exp2(-(k+q)))
__global__ void k_edge2(const int* __restrict__ off_rd, const int* __restrict__ pk_rd,
                        const unsigned short* __restrict__ kqv,
                        const unsigned short* __restrict__ skipb,
                        float* __restrict__ out, int n){
  int wid = blockIdx.x*(blockDim.x >> 6) + (threadIdx.x >> 6);
  int lane = threadIdx.x & 63;
  if (wid >= n) return;
  const uint32_t* kv32 = (const uint32_t*)kqv;
  int r = lane & 7;
  int o_r = off_rd[(size_t)r*n + wid];
  int e_r = off_rd[(size_t)r*n + wid + 1];
  int c_r = e_r - o_r;
  int c0_ = __builtin_amdgcn_readlane(c_r, 0), c1_ = __builtin_amdgcn_readlane(c_r, 1);
  int c2_ = __builtin_amdgcn_readlane(c_r, 2), c3_ = __builtin_amdgcn_readlane(c_r, 3);
  int c4_ = __builtin_amdgcn_readlane(c_r, 4), c5_ = __builtin_amdgcn_readlane(c_r, 5);
  int c6_ = __builtin_amdgcn_readlane(c_r, 6), c7_ = __builtin_amdgcn_readlane(c_r, 7);
  int o0_ = __builtin_amdgcn_readlane(o_r, 0), o1_ = __builtin_amdgcn_readlane(o_r, 1);
  int o2_ = __builtin_amdgcn_readlane(o_r, 2), o3_ = __builtin_amdgcn_readlane(o_r, 3);
  int o4_ = __builtin_amdgcn_readlane(o_r, 4), o5_ = __builtin_amdgcn_readlane(o_r, 5);
  int o6_ = __builtin_amdgcn_readlane(o_r, 6), o7_ = __builtin_amdgcn_readlane(o_r, 7);
  int p1 = c0_, p2 = p1 + c1_, p3 = p2 + c2_, p4 = p3 + c3_;
  int p5 = p4 + c4_, p6 = p5 + c5_, p7 = p6 + c6_, dg = p7 + c7_;

  uint32_t ku = kv32[(size_t)wid*192 + lane];
  float k0 = bf2f(ku), k1 = bf2f(ku >> 16);
  float a0 = 0.f, a1 = 0.f;
  for (int jb = 0; jb < dg; jb += 64){
    int i = jb + lane;
    int adj = o0_;
    adj = (i >= p1) ? (o1_ - p1) : adj;
    adj = (i >= p2) ? (o2_ - p2) : adj;
    adj = (i >= p3) ? (o3_ - p3) : adj;
    adj = (i >= p4) ? (o4_ - p4) : adj;
    adj = (i >= p5) ? (o5_ - p5) : adj;
    adj = (i >= p6) ? (o6_ - p6) : adj;
    adj = (i >= p7) ? (o7_ - p7) : adj;
    int m = dg - jb; if (m > 64) m = 64;
    int pj = (lane < m) ? pk_rd[adj + i] : 0;
    int jj = 0;
    for (; jj + 8 <= m; jj += 8){
      uint32_t qg[8], vg[8];
      #pragma unroll
      for (int k = 0; k < 8; ++k){
        int s = __builtin_amdgcn_readlane(pj, jj + k);
        const uint32_t* rowp = kv32 + (size_t)s*192 + lane;
        qg[k] = rowp[64];
        vg[k] = rowp[128];
      }
      #pragma unroll
      for (int k = 0; k < 8; ++k){
        float qq0 = bf2f(qg[k]), qq1 = bf2f(qg[k] >> 16);
        float vv0 = bf2f(vg[k]), vv1 = bf2f(vg[k] >> 16);
        float g0 = __builtin_amdgcn_rcpf(1.f + __builtin_amdgcn_exp2f(-(k0 + qq0)));
        float g1 = __builtin_amdgcn_rcpf(1.f + __builtin_amdgcn_exp2f(-(k1 + qq1)));
        a0 += g0*vv0; a1 += g1*vv1;
      }
    }
    for (; jj + 4 <= m; jj += 4){
      uint32_t qg[4], vg[4];
      #pragma unroll
      for (int k = 0; k < 4; ++k){
        int s = __builtin_amdgcn_readlane(pj, jj + k);
        const uint32_t* rowp = kv32 + (size_t)s*192 + lane;
        qg[k] = rowp[64];
        vg[k] = rowp[128];
      }
      #pragma unroll
      for (int k = 0; k < 4; ++k){
        float qq0 = bf2f(qg[k]), qq1 = bf2f(qg[k] >> 16);
        float vv0 = bf2f(vg[k]), vv1 = bf2f(vg[k] >> 16);
        float g0 = __builtin_amdgcn_rcpf(1.f + __builtin_amdgcn_exp2f(-(k0 + qq0)));
        float g1 = __builtin_amdgcn_rcpf(1.f + __builtin_amdgcn_exp2f(-(k1 + qq1)));
        a0 += g0*vv0; a1 += g1*vv1;
      }
    }
    for (; jj < m; ++jj){
      int s = __builtin_amdgcn_readlane(pj, jj);
      const uint32_t* rowp = kv32 + (size_t)s*192 + lane;
      uint32_t qg = rowp[64], vg = rowp[128];
      float qq0 = bf2f(qg), qq1 = bf2f(qg >> 16);
      float vv0 = bf2f(vg), vv1 = bf2f(vg >> 16);
      float g0 = __builtin_amdgcn_rcpf(1.f + __builtin_amdgcn_exp2f(-(k0 + qq0)));
      float g1 = __builtin_amdgcn_rcpf(1.f + __builtin_amdgcn_exp2f(-(k1 + qq1)));
      a0 += g0*vv0; a1 += g1*vv1;
    }
  }
  uint32_t sk = ((const uint32_t*)skipb)[(size_t)wid*64 + lane];
  float2 cur; cur.x = a0 + bf2f(sk); cur.y = a1 + bf2f(sk >> 16);
  ((float2*)(out + (size_t)wid*H2))[lane] = cur;
}

extern "C" void kernel_launch(void* const* d_in, const int* in_sizes, int n_in,
                              void* d_out, int out_size, void* d_ws, size_t ws_size,
                              hipStream_t stream){
  const float* x     = (const float*)d_in[0];
  const int*   eidx  = (const int*)  d_in[1];
  const int*   etype = (const int*)  d_in[3];
  const float* basis = (const float*)d_in[4];
  const float* comp  = (const float*)d_in[5];
  const float* root  = (const float*)d_in[6];
  const float* bias1 = (const float*)d_in[7];
  const float* wk    = (const float*)d_in[8];
  const float* bk    = (const float*)d_in[9];
  const float* wq    = (const float*)d_in[10];
  const float* bq    = (const float*)d_in[11];
  const float* wv    = (const float*)d_in[12];
  const float* bv    = (const float*)d_in[13];
  const float* wsk   = (const float*)d_in[14];
  const float* bs    = (const float*)d_in[15];
  const int n = in_sizes[0] / GD;          // 50000
  const int E = in_sizes[3];               // 600000
  const int npad = (n + 127) & ~127;       // 50048
  const int* esrc = eidx;
  const int* edst = eidx + E;
  float* out = (float*)d_out;

  char* w = (char*)d_ws;
  size_t off = 0;
  unsigned short* xbf  = (unsigned short*)(w + off); off = align256(off + (size_t)npad*GD*2);
  unsigned short* A2   = (unsigned short*)(w + off); off = align256(off + (size_t)npad*1024*2);
  unsigned short* Bht  = (unsigned short*)(w + off); off = align256(off + (size_t)KA*H1*2);
  unsigned short* B2t  = (unsigned short*)(w + off); off = align256(off + (size_t)512*H1*2);
  float* Bb            = (float*)(w + off);          off = align256(off + 512*4);
  unsigned short* kqv  = (unsigned short*)(w + off); off = align256(off + (size_t)npad*384*2);
  unsigned short* skipb= (unsigned short*)(w + off); off = align256(off + (size_t)npad*H2*2);
  int* cnt_rd          = (int*)(w + off);            off = align256(off + (size_t)(8*n+4)*4);
  int* off_rd          = (int*)(w + off);            off = align256(off + (size_t)(8*n+1)*4);
  int* cur_rd          = (int*)(w + off);            off = align256(off + (size_t)8*n*4);
  int* btot_rd         = (int*)(w + off);            off = align256(off + 64*4);
  int* pk_rd           = (int*)(w + off);            off = align256(off + (size_t)E*4);

  const int nblk_rd = (8*n + 8191) / 8192;       // 49
  const int cnt4 = n*GD/4;                       // 1.6M
  const int ncastb = (cnt4 + 1023)/1024;         // 1563
  const int histb  = (E + 255)/256;              // 2344
  const int npadz  = (npad - n)*GD/2;            // pad uint32 count

  hipMemsetAsync(cnt_rd, 0, (size_t)8*n*4, stream);

  k_prep<<<128 + 256 + ncastb + 12 + histb, 256, 0, stream>>>(
      comp, basis, root, Bht, wk, wq, wv, wsk, bk, bq, bv, bs, B2t, Bb,
      (const float4*)x, (uint2*)xbf, cnt4,
      (uint32_t*)(xbf + (size_t)n*GD), npadz,
      edst, etype, cnt_rd, E, n);
  k_scanA<<<nblk_rd, 1024, 0, stream>>>(cnt_rd, off_rd, btot_rd, 8*n);
  k_scanB<<<nblk_rd, 1024, 0, stream>>>(btot_rd, off_rd, cur_rd, 8*n, E);
  k_scatter_rd<<<(E + 255)/256, 256, 0, stream>>>(esrc, edst, etype, cur_rd, pk_rd, E, n);
  k_agg<<<(npad + 3)/4, 256, 0, stream>>>(off_rd, pk_rd, (const uint32_t*)xbf, A2, n, npad);
  k_hqkv<<<npad/64, 256, 0, stream>>>(A2, xbf, Bht, B2t, bias1, Bb, kqv, skipb);
  k_edge2<<<(n + 3)/4, 256, 0, stream>>>(off_rd, pk_rd, kqv, skipb, out, n);
}

// Round 11
// 334.944 us; speedup vs baseline: 1.0118x; 1.0118x over previous
//
#include <hip/hip_runtime.h>
#include <stdint.h>

#define GD 128
#define H1 128
#define H2 128
#define NBASES 32
#define NREL 8
#define KA 1152   // logical K = 8*128 (relation means) + 128 (x | root)

typedef __attribute__((ext_vector_type(8))) short bf16x8;
typedef __attribute__((ext_vector_type(4))) float f32x4;

static inline size_t align256(size_t x){ return (x + 255) & ~(size_t)255; }

__device__ __forceinline__ float bf2f(uint32_t u16){
  union { uint32_t u; float f; } c; c.u = (u16 & 0xffffu) << 16; return c.f;
}
__device__ __forceinline__ unsigned short f2bf(float f){
  union { float f; uint32_t u; } c; c.f = f;
  uint32_t u = c.u;
  u += 0x7fffu + ((u >> 16) & 1u);   // RTNE (finite inputs)
  return (unsigned short)(u >> 16);
}
__device__ __forceinline__ uint32_t pkbf(float a, float b){
  union { float f; uint32_t u; } ca, cb; ca.f = a; cb.f = b;
  return __builtin_amdgcn_perm(cb.u + 0x8000u, ca.u + 0x8000u, 0x07060302u);
}

__device__ __forceinline__ void async_copy16(void* lds_dst, const void* gsrc){
  __builtin_amdgcn_global_load_lds(
      (const __attribute__((address_space(1))) uint32_t*)gsrc,
      (__attribute__((address_space(3))) uint32_t*)lds_dst, 16, 0, 0);
}

// ==== merged prep: Bht build (coalesced) | B2t build (log2e prescale) | x cast | xbf pad zero | hist ====
__global__ void k_prep(const float* __restrict__ comp, const float* __restrict__ basis,
                       const float* __restrict__ root, unsigned short* __restrict__ Bht,
                       const float* __restrict__ wk, const float* __restrict__ wq,
                       const float* __restrict__ wv, const float* __restrict__ wsk,
                       const float* __restrict__ bk, const float* __restrict__ bq,
                       const float* __restrict__ bv, const float* __restrict__ bs,
                       unsigned short* __restrict__ B2t, float* __restrict__ Bb,
                       const float4* __restrict__ x, uint2* __restrict__ xout, int cnt4,
                       uint32_t* __restrict__ xpadz, int npadz,
                       const int* __restrict__ edst, const int* __restrict__ etyp,
                       int* __restrict__ cnt, int E, int n){
  const float LOG2E = 1.4426950408889634f;
  int b = blockIdx.x, t = threadIdx.x;
  if (b < 128){
    // block = K-row i; lane = output col o (coalesced basis reads, 256B/wave segments)
    int i = b;
    int o = t & 127, rh = t >> 7;
    float bv[NBASES];
    #pragma unroll
    for (int bb = 0; bb < NBASES; ++bb)
      bv[bb] = basis[((size_t)bb*GD + i)*H1 + o];
    #pragma unroll
    for (int rr = 0; rr < 4; ++rr){
      int r = rh*4 + rr;
      float acc = 0.f;
      #pragma unroll
      for (int bb = 0; bb < NBASES; ++bb)
        acc += comp[r*NBASES + bb] * bv[bb];
      Bht[(size_t)o*KA + r*128 + i] = f2bf(acc);
    }
    if (rh == 1) Bht[(size_t)o*KA + 1024 + i] = f2bf(root[(size_t)i*H1 + o]);
  } else if (b < 128 + 256){
    int idx = (b - 128)*256 + t;         // < 65536 = 512*H1
    int c = idx / H1, k = idx % H1;
    const float* w = (c < 128) ? wk : (c < 256) ? wq : (c < 384) ? wv : wsk;
    float val = w[(size_t)k*H2 + (c & 127)];
    if (c < 256) val *= LOG2E;           // fold log2e into k,q so edge2 uses raw v_exp
    B2t[idx] = f2bf(val);
    if (idx < 512){
      const float* bia = (idx < 128) ? bk : (idx < 256) ? bq : (idx < 384) ? bv : bs;
      float bval = bia[idx & 127];
      if (idx < 256) bval *= LOG2E;
      Bb[idx] = bval;
    }
  } else {
    int cb = b - (128 + 256);
    int ncastb = (cnt4 + 1023) >> 10;
    if (cb < ncastb){
      int base = cb*1024 + t;
      #pragma unroll
      for (int u = 0; u < 4; ++u){
        int i = base + u*256;
        if (i < cnt4){
          float4 v = x[i];
          uint2 o; o.x = pkbf(v.x, v.y); o.y = pkbf(v.z, v.w);
          xout[i] = o;
        }
      }
    } else if (cb < ncastb + 12){
      int i = (cb - ncastb)*256 + t;
      if (i < npadz) xpadz[i] = 0u;      // zero xbf pad rows (hqkv root chunk reads them)
    } else {
      int e = (cb - ncastb - 12)*256 + t;
      if (e < E) atomicAdd(&cnt[etyp[e]*n + edst[e]], 1);
    }
  }
}

// ---- parallel scan, stage A ----
__global__ void k_scanA(const int* __restrict__ deg, int* __restrict__ off,
                        int* __restrict__ btot, int len){
  __shared__ int wsum[16];
  int t = threadIdx.x, lane = t & 63, w = t >> 6;
  int i0 = blockIdx.x*8192 + t*8;
  int v[8];
  if (i0 + 7 < len){
    int4 va = *(const int4*)(deg + i0);
    int4 vb = *(const int4*)(deg + i0 + 4);
    v[0]=va.x; v[1]=va.y; v[2]=va.z; v[3]=va.w;
    v[4]=vb.x; v[5]=vb.y; v[6]=vb.z; v[7]=vb.w;
  } else {
    #pragma unroll
    for (int u = 0; u < 8; ++u) v[u] = (i0+u < len) ? deg[i0+u] : 0;
  }
  int s[8]; s[0] = v[0];
  #pragma unroll
  for (int u = 1; u < 8; ++u) s[u] = s[u-1] + v[u];
  int x = s[7];
  #pragma unroll
  for (int d = 1; d < 64; d <<= 1){
    int u = __shfl_up(x, d, 64);
    if (lane >= d) x += u;
  }
  if (lane == 63) wsum[w] = x;
  __syncthreads();
  if (t < 16){
    int y = wsum[t];
    #pragma unroll
    for (int d = 1; d < 16; d <<= 1){
      int u = __shfl_up(y, d, 16);
      if (t >= d) y += u;
    }
    wsum[t] = y;
  }
  __syncthreads();
  int woff = (w > 0) ? wsum[w-1] : 0;
  int excl = woff + x - s[7];
  #pragma unroll
  for (int u = 0; u < 8; ++u)
    if (i0+u < len) off[i0+u] = excl + s[u] - v[u];
  if (t == 0) btot[blockIdx.x] = wsum[15];
}

// ---- scan stage B ----
__global__ void k_scanB(const int* __restrict__ btot, int* __restrict__ off,
                        int* __restrict__ cursor, int len, int sentinel){
  int t = threadIdx.x, bid = blockIdx.x;
  int add = 0;
  for (int j = 0; j < bid; ++j) add += btot[j];
  int i0 = bid*8192 + t*8;
  #pragma unroll
  for (int u = 0; u < 8; ++u){
    int i = i0 + u;
    if (i < len){ int val = off[i] + add; off[i] = val; cursor[i] = val; }
  }
  if (bid == 0 && t == 0) off[len] = sentinel;
}

// pk[pos] = src, (r,dst)-sorted
__global__ void k_scatter_rd(const int* __restrict__ src, const int* __restrict__ dst,
                             const int* __restrict__ typ, int* __restrict__ cursor,
                             int* __restrict__ pk, int E, int n){
  int e = blockIdx.x*blockDim.x + threadIdx.x;
  if (e >= E) return;
  int pos = atomicAdd(&cursor[typ[e]*n + dst[e]], 1);
  pk[pos] = src[e];
}

// ---- one wave per dst node: A2[d] = [mean_r(x_src) for r=0..7] (bf16, width 1024) ----
// merged-relation pipelined gather: batched 8 across relation boundaries,
// scalar-uniform flush when the (sorted) relation id changes. Zero barriers, max occupancy.
__global__ void k_agg(const int* __restrict__ off_rd, const int* __restrict__ pk_rd,
                      const uint32_t* __restrict__ x32, unsigned short* __restrict__ A2,
                      int n, int npad){
  int wid = blockIdx.x*(blockDim.x >> 6) + (threadIdx.x >> 6);
  int lane = threadIdx.x & 63;
  if (wid >= npad) return;
  uint32_t* arow = (uint32_t*)(A2 + (size_t)wid*1024);
  if (wid >= n){
    #pragma unroll
    for (int u = 0; u < 8; ++u) arow[u*64 + lane] = 0u;
    return;
  }
  int r8 = lane & 7;
  int o_r = off_rd[(size_t)r8*n + wid];
  int e_r = off_rd[(size_t)r8*n + wid + 1];
  int c_r = e_r - o_r;
  float ic_r = (c_r > 0) ? __builtin_amdgcn_rcpf((float)c_r) : 0.f;
  int c0_ = __builtin_amdgcn_readlane(c_r, 0), c1_ = __builtin_amdgcn_readlane(c_r, 1);
  int c2_ = __builtin_amdgcn_readlane(c_r, 2), c3_ = __builtin_amdgcn_readlane(c_r, 3);
  int c4_ = __builtin_amdgcn_readlane(c_r, 4), c5_ = __builtin_amdgcn_readlane(c_r, 5);
  int c6_ = __builtin_amdgcn_readlane(c_r, 6), c7_ = __builtin_amdgcn_readlane(c_r, 7);
  int o0_ = __builtin_amdgcn_readlane(o_r, 0), o1_ = __builtin_amdgcn_readlane(o_r, 1);
  int o2_ = __builtin_amdgcn_readlane(o_r, 2), o3_ = __builtin_amdgcn_readlane(o_r, 3);
  int o4_ = __builtin_amdgcn_readlane(o_r, 4), o5_ = __builtin_amdgcn_readlane(o_r, 5);
  int o6_ = __builtin_amdgcn_readlane(o_r, 6), o7_ = __builtin_amdgcn_readlane(o_r, 7);
  int p1 = c0_, p2 = p1 + c1_, p3 = p2 + c2_, p4 = p3 + c3_;
  int p5 = p4 + c4_, p6 = p5 + c5_, p7 = p6 + c6_, dg = p7 + c7_;

  int cr = 0;                 // relation currently being accumulated (edges are rel-sorted)
  float a0 = 0.f, a1 = 0.f;

#define FLUSH(RK)                                                               \
  {                                                                             \
    float ic = __int_as_float(__builtin_amdgcn_readlane(__float_as_int(ic_r), cr)); \
    arow[cr*64 + lane] = pkbf(a0*ic, a1*ic);                                    \
    for (int q = cr + 1; q < (RK); ++q) arow[q*64 + lane] = 0u;                 \
    cr = (RK); a0 = 0.f; a1 = 0.f;                                              \
  }

  for (int jb = 0; jb < dg; jb += 64){
    int i = jb + lane;
    int adj = o0_, rel = 0;
    adj = (i >= p1) ? (o1_ - p1) : adj;  rel += (i >= p1);
    adj = (i >= p2) ? (o2_ - p2) : adj;  rel += (i >= p2);
    adj = (i >= p3) ? (o3_ - p3) : adj;  rel += (i >= p3);
    adj = (i >= p4) ? (o4_ - p4) : adj;  rel += (i >= p4);
    adj = (i >= p5) ? (o5_ - p5) : adj;  rel += (i >= p5);
    adj = (i >= p6) ? (o6_ - p6) : adj;  rel += (i >= p6);
    adj = (i >= p7) ? (o7_ - p7) : adj;  rel += (i >= p7);
    int m = dg - jb; if (m > 64) m = 64;
    int pj = (lane < m) ? pk_rd[adj + i] : 0;
    int jj = 0;
    for (; jj + 8 <= m; jj += 8){
      uint32_t g[8];
      #pragma unroll
      for (int k = 0; k < 8; ++k){
        int sN = __builtin_amdgcn_readlane(pj, jj + k);
        g[k] = x32[(size_t)(uint32_t)sN*64 + lane];
      }
      #pragma unroll
      for (int k = 0; k < 8; ++k){
        int rk = __builtin_amdgcn_readlane(rel, jj + k);
        if (rk != cr) FLUSH(rk);
        a0 += bf2f(g[k]); a1 += bf2f(g[k] >> 16);
      }
    }
    for (; jj < m; jj += 4){             // padded batch-4 tail: keeps 4 loads in flight
      int lim = m - 1;
      uint32_t g[4];
      #pragma unroll
      for (int k = 0; k < 4; ++k){
        int tt = jj + k; if (tt > lim) tt = lim;
        int sN = __builtin_amdgcn_readlane(pj, tt);
        g[k] = x32[(size_t)(uint32_t)sN*64 + lane];
      }
      #pragma unroll
      for (int k = 0; k < 4; ++k){
        int tt = jj + k;
        if (tt < m){
          int rk = __builtin_amdgcn_readlane(rel, tt);
          if (rk != cr) FLUSH(rk);
          a0 += bf2f(g[k]); a1 += bf2f(g[k] >> 16);
        }
      }
    }
  }
  FLUSH(8)                               // write last accumulated rel + trailing zeros
#undef FLUSH
}

// ---- fused hgemm+gemm2 (k_hqkv v2): stage-ahead double-buffered pipeline.
//      GEMM1: h_tile[64][128] = [A2|xbf] @ Bht^T + bias1 -> LDS (bf16, XOR-swizzled);
//      GEMM2: h_tile @ B2t + Bb -> kqv/skipb. Per step: STAGE(next) BEFORE compute(cur)
//      so async loads fly under the MFMA phase; one barrier per step.
__launch_bounds__(256)
__global__ void k_hqkv(const unsigned short* __restrict__ A, const unsigned short* __restrict__ xb,
                       const unsigned short* __restrict__ Bt,   // Bht [128][1152]
                       const unsigned short* __restrict__ B2,   // B2t [512][128]
                       const float* __restrict__ bias1, const float* __restrict__ Bb,
                       unsigned short* __restrict__ kqv, unsigned short* __restrict__ skipb){
  __shared__ char lds[49664];  // [0,16K): B dbuf 2x8K; [16K,32K): htile; [32K,48.9K): eb (GEMM2) / A dbuf 2x4K (GEMM1)
  int t = threadIdx.x, lane = t & 63, wave = t >> 6;
  int row0 = blockIdx.x * 64;
  int mrow = lane & 15, quad = lane >> 4;
  int s = (mrow >> 1) & 3;
  int colsw = (((t & 3) ^ ((t >> 3) & 3)) << 3);

  const unsigned short* Asrc = A  + (size_t)(row0 + (t >> 2))*1024 + colsw;
  const unsigned short* Xsrc = xb + (size_t)(row0 + (t >> 2))*GD   + colsw;
  const unsigned short* Bsrc = Bt + (size_t)(t >> 2)*KA + colsw;
  const unsigned short* B2src = B2 + (size_t)(t >> 2)*H1 + colsw;
  char* Bstg  = lds;
  char* htile = lds + 16384;
  char* Astg  = lds + 32768;
  char* eb    = lds + 32768;

  int aoff = mrow*64 + ((quad ^ s) << 4);
  int boff = (wave*32 + mrow)*64 + ((quad ^ s) << 4);
  int axor = (mrow & 7) << 4;

  f32x4 acc[4][2];
  #pragma unroll
  for (int i = 0; i < 4; ++i)
    #pragma unroll
    for (int j = 0; j < 2; ++j) acc[i][j] = (f32x4){0.f,0.f,0.f,0.f};

#define STAGE1(B_, KT_)                                                           \
  { const unsigned short* ap = ((KT_) < 1024) ? (Asrc + (KT_)) : (Xsrc + ((KT_) - 1024)); \
    async_copy16(Astg + (B_)*4096 + wave*1024, ap);                               \
    async_copy16(Bstg + (B_)*8192 + wave*1024, Bsrc + (KT_));                     \
    async_copy16(Bstg + (B_)*8192 + 4096 + wave*1024, Bsrc + (size_t)64*KA + (KT_)); }

  // ---- GEMM1: K = 1152, stage-ahead dbuf, 1 barrier/step ----
  STAGE1(0, 0)
  __syncthreads();
  int b = 0;
  for (int step = 0; step < 36; ++step){
    if (step < 35) STAGE1(b^1, (step+1)*32)
    bf16x8 af[4], bf[2];
    #pragma unroll
    for (int i = 0; i < 4; ++i) af[i] = *(const bf16x8*)(Astg + b*4096 + aoff + i*1024);
    #pragma unroll
    for (int j = 0; j < 2; ++j) bf[j] = *(const bf16x8*)(Bstg + b*8192 + boff + j*1024);
    #pragma unroll
    for (int i = 0; i < 4; ++i)
      #pragma unroll
      for (int j = 0; j < 2; ++j)
        acc[i][j] = __builtin_amdgcn_mfma_f32_16x16x32_bf16(af[i], bf[j], acc[i][j], 0, 0, 0);
    __syncthreads();
    b ^= 1;
  }
#undef STAGE1

  // ---- h-tile to LDS (bias + bf16, 256B rows, 16B-block XOR swizzle) ----
  {
    float bc1[2];
    #pragma unroll
    for (int j = 0; j < 2; ++j) bc1[j] = bias1[wave*32 + j*16 + mrow];
    #pragma unroll
    for (int j = 0; j < 2; ++j){
      int col = wave*32 + j*16 + mrow;
      #pragma unroll
      for (int i = 0; i < 4; ++i)
        #pragma unroll
        for (int rg = 0; rg < 4; ++rg){
          int row = i*16 + quad*4 + rg;
          *(unsigned short*)(htile + row*256 + ((col*2) ^ ((row & 7) << 4)))
              = f2bf(acc[i][j][rg] + bc1[j]);
        }
    }
  }

#define STAGE2(B_, C0_, KT_)                                                      \
  { async_copy16(Bstg + (B_)*8192 + wave*1024, B2src + (C0_)*16384 + (KT_));      \
    async_copy16(Bstg + (B_)*8192 + 4096 + wave*1024,                             \
                 B2src + (C0_)*16384 + (size_t)64*H1 + (KT_)); }

  // prologue for GEMM2: stage (c0=0, kt=0) into Bstg[b]; barrier makes htile visible + drains
  STAGE2(b, 0, 0)
  __syncthreads();

  // ---- GEMM2: 16 unified (chunk, kt) steps, stage-ahead dbuf ----
  for (int idx = 0; idx < 16; ++idx){
    int ks = idx & 3;
    if (idx < 15) STAGE2(b^1, (idx+1) >> 2, ((idx+1) & 3)*32)
    if (ks == 0){
      #pragma unroll
      for (int i = 0; i < 4; ++i)
        #pragma unroll
        for (int j = 0; j < 2; ++j) acc[i][j] = (f32x4){0.f,0.f,0.f,0.f};
    }
    int kt = ks*32;
    bf16x8 af[4], bf[2];
    #pragma unroll
    for (int i = 0; i < 4; ++i)
      af[i] = *(const bf16x8*)(htile + (i*16 + mrow)*256 + (((kt + quad*8)*2) ^ axor));
    #pragma unroll
    for (int j = 0; j < 2; ++j) bf[j] = *(const bf16x8*)(Bstg + b*8192 + boff + j*1024);
    #pragma unroll
    for (int i = 0; i < 4; ++i)
      #pragma unroll
      for (int j = 0; j < 2; ++j)
        acc[i][j] = __builtin_amdgcn_mfma_f32_16x16x32_bf16(af[i], bf[j], acc[i][j], 0, 0, 0);
    if (ks == 3){
      int c0 = idx >> 2;
      // epilogue: bias + bf16 -> eb transpose buffer -> coalesced stores
      float bc2[2];
      #pragma unroll
      for (int j = 0; j < 2; ++j) bc2[j] = Bb[c0*128 + wave*32 + j*16 + mrow];
      #pragma unroll
      for (int j = 0; j < 2; ++j){
        int col = wave*32 + j*16 + mrow;
        #pragma unroll
        for (int i = 0; i < 4; ++i)
          #pragma unroll
          for (int rg = 0; rg < 4; ++rg){
            int rl = i*16 + quad*4 + rg;
            *(unsigned short*)(eb + rl*264 + col*2) = f2bf(acc[i][j][rg] + bc2[j]);
          }
      }
      __syncthreads();   // eb visible + stage drained; doubles as step barrier
      uint32_t vv[16];
      #pragma unroll
      for (int u = 0; u < 8; ++u)
        *(uint2*)&vv[u*2] = *(const uint2*)(eb + lane*264 + wave*64 + u*8);
      unsigned short* dstb; size_t ldu;
      if (c0 < 3){ dstb = kqv + c0*128; ldu = 384; } else { dstb = skipb; ldu = 128; }
      unsigned short* gp = dstb + (size_t)(row0 + lane)*ldu + wave*32;
      #pragma unroll
      for (int u = 0; u < 4; ++u)
        *(uint4*)(gp + u*8) = *(const uint4*)&vv[u*4];
      // eb reads complete before next epilogue's writes: 3 step barriers intervene
    } else {
      __syncthreads();
    }
    b ^= 1;
  }
#undef STAGE2
}

// ---- one wave per dst node: out = sum_e sigmoid(k+q)*v + skip (pure write) ----
// kqv layout: [row][k(128)|q(128)|v(128)]; k,q prescaled by log2e: sigmoid = rcp(1+exp2(-(k+q)))
__global__ void k_edge2(const int* __restrict__ off_rd, const int* __restrict__ pk_rd,
                        const unsigned short* __restrict__ kqv,
                        const unsigned short* __restrict__ skipb,
                        float* __restrict__ out, int n){
  int wid = blockIdx.x*(blockDim.x >> 6) + (threadIdx.x >> 6);
  int lane = threadIdx.x & 63;
  if (wid >= n) return;
  const uint32_t* kv32 = (const uint32_t*)kqv;
  int r = lane & 7;
  int o_r = off_rd[(size_t)r*n + wid];
  int e_r = off_rd[(size_t)r*n + wid + 1];
  int c_r = e_r - o_r;
  int c0_ = __builtin_amdgcn_readlane(c_r, 0), c1_ = __builtin_amdgcn_readlane(c_r, 1);
  int c2_ = __builtin_amdgcn_readlane(c_r, 2), c3_ = __builtin_amdgcn_readlane(c_r, 3);
  int c4_ = __builtin_amdgcn_readlane(c_r, 4), c5_ = __builtin_amdgcn_readlane(c_r, 5);
  int c6_ = __builtin_amdgcn_readlane(c_r, 6), c7_ = __builtin_amdgcn_readlane(c_r, 7);
  int o0_ = __builtin_amdgcn_readlane(o_r, 0), o1_ = __builtin_amdgcn_readlane(o_r, 1);
  int o2_ = __builtin_amdgcn_readlane(o_r, 2), o3_ = __builtin_amdgcn_readlane(o_r, 3);
  int o4_ = __builtin_amdgcn_readlane(o_r, 4), o5_ = __builtin_amdgcn_readlane(o_r, 5);
  int o6_ = __builtin_amdgcn_readlane(o_r, 6), o7_ = __builtin_amdgcn_readlane(o_r, 7);
  int p1 = c0_, p2 = p1 + c1_, p3 = p2 + c2_, p4 = p3 + c3_;
  int p5 = p4 + c4_, p6 = p5 + c5_, p7 = p6 + c6_, dg = p7 + c7_;

  uint32_t ku = kv32[(size_t)wid*192 + lane];
  float k0 = bf2f(ku), k1 = bf2f(ku >> 16);
  float a0 = 0.f, a1 = 0.f;
  for (int jb = 0; jb < dg; jb += 64){
    int i = jb + lane;
    int adj = o0_;
    adj = (i >= p1) ? (o1_ - p1) : adj;
    adj = (i >= p2) ? (o2_ - p2) : adj;
    adj = (i >= p3) ? (o3_ - p3) : adj;
    adj = (i >= p4) ? (o4_ - p4) : adj;
    adj = (i >= p5) ? (o5_ - p5) : adj;
    adj = (i >= p6) ? (o6_ - p6) : adj;
    adj = (i >= p7) ? (o7_ - p7) : adj;
    int m = dg - jb; if (m > 64) m = 64;
    int pj = (lane < m) ? pk_rd[adj + i] : 0;
    int jj = 0;
    for (; jj + 8 <= m; jj += 8){
      uint32_t qg[8], vg[8];
      #pragma unroll
      for (int k = 0; k < 8; ++k){
        int s = __builtin_amdgcn_readlane(pj, jj + k);
        const uint32_t* rowp = kv32 + (size_t)s*192 + lane;
        qg[k] = rowp[64];
        vg[k] = rowp[128];
      }
      #pragma unroll
      for (int k = 0; k < 8; ++k){
        float qq0 = bf2f(qg[k]), qq1 = bf2f(qg[k] >> 16);
        float vv0 = bf2f(vg[k]), vv1 = bf2f(vg[k] >> 16);
        float g0 = __builtin_amdgcn_rcpf(1.f + __builtin_amdgcn_exp2f(-(k0 + qq0)));
        float g1 = __builtin_amdgcn_rcpf(1.f + __builtin_amdgcn_exp2f(-(k1 + qq1)));
        a0 += g0*vv0; a1 += g1*vv1;
      }
    }
    for (; jj + 4 <= m; jj += 4){
      uint32_t qg[4], vg[4];
      #pragma unroll
      for (int k = 0; k < 4; ++k){
        int s = __builtin_amdgcn_readlane(pj, jj + k);
        const uint32_t* rowp = kv32 + (size_t)s*192 + lane;
        qg[k] = rowp[64];
        vg[k] = rowp[128];
      }
      #pragma unroll
      for (int k = 0; k < 4; ++k){
        float qq0 = bf2f(qg[k]), qq1 = bf2f(qg[k] >> 16);
        float vv0 = bf2f(vg[k]), vv1 = bf2f(vg[k] >> 16);
        float g0 = __builtin_amdgcn_rcpf(1.f + __builtin_amdgcn_exp2f(-(k0 + qq0)));
        float g1 = __builtin_amdgcn_rcpf(1.f + __builtin_amdgcn_exp2f(-(k1 + qq1)));
        a0 += g0*vv0; a1 += g1*vv1;
      }
    }
    for (; jj < m; ++jj){
      int s = __builtin_amdgcn_readlane(pj, jj);
      const uint32_t* rowp = kv32 + (size_t)s*192 + lane;
      uint32_t qg = rowp[64], vg = rowp[128];
      float qq0 = bf2f(qg), qq1 = bf2f(qg >> 16);
      float vv0 = bf2f(vg), vv1 = bf2f(vg >> 16);
      float g0 = __builtin_amdgcn_rcpf(1.f + __builtin_amdgcn_exp2f(-(k0 + qq0)));
      float g1 = __builtin_amdgcn_rcpf(1.f + __builtin_amdgcn_exp2f(-(k1 + qq1)));
      a0 += g0*vv0; a1 += g1*vv1;
    }
  }
  uint32_t sk = ((const uint32_t*)skipb)[(size_t)wid*64 + lane];
  float2 cur; cur.x = a0 + bf2f(sk); cur.y = a1 + bf2f(sk >> 16);
  ((float2*)(out + (size_t)wid*H2))[lane] = cur;
}

extern "C" void kernel_launch(void* const* d_in, const int* in_sizes, int n_in,
                              void* d_out, int out_size, void* d_ws, size_t ws_size,
                              hipStream_t stream){
  const float* x     = (const float*)d_in[0];
  const int*   eidx  = (const int*)  d_in[1];
  const int*   etype = (const int*)  d_in[3];
  const float* basis = (const float*)d_in[4];
  const float* comp  = (const float*)d_in[5];
  const float* root  = (const float*)d_in[6];
  const float* bias1 = (const float*)d_in[7];
  const float* wk    = (const float*)d_in[8];
  const float* bk    = (const float*)d_in[9];
  const float* wq    = (const float*)d_in[10];
  const float* bq    = (const float*)d_in[11];
  const float* wv    = (const float*)d_in[12];
  const float* bv    = (const float*)d_in[13];
  const float* wsk   = (const float*)d_in[14];
  const float* bs    = (const float*)d_in[15];
  const int n = in_sizes[0] / GD;          // 50000
  const int E = in_sizes[3];               // 600000
  const int npad = (n + 127) & ~127;       // 50048
  const int* esrc = eidx;
  const int* edst = eidx + E;
  float* out = (float*)d_out;

  char* w = (char*)d_ws;
  size_t off = 0;
  unsigned short* xbf  = (unsigned short*)(w + off); off = align256(off + (size_t)npad*GD*2);
  unsigned short* A2   = (unsigned short*)(w + off); off = align256(off + (size_t)npad*1024*2);
  unsigned short* Bht  = (unsigned short*)(w + off); off = align256(off + (size_t)KA*H1*2);
  unsigned short* B2t  = (unsigned short*)(w + off); off = align256(off + (size_t)512*H1*2);
  float* Bb            = (float*)(w + off);          off = align256(off + 512*4);
  unsigned short* kqv  = (unsigned short*)(w + off); off = align256(off + (size_t)npad*384*2);
  unsigned short* skipb= (unsigned short*)(w + off); off = align256(off + (size_t)npad*H2*2);
  int* cnt_rd          = (int*)(w + off);            off = align256(off + (size_t)(8*n+4)*4);
  int* off_rd          = (int*)(w + off);            off = align256(off + (size_t)(8*n+1)*4);
  int* cur_rd          = (int*)(w + off);            off = align256(off + (size_t)8*n*4);
  int* btot_rd         = (int*)(w + off);            off = align256(off + 64*4);
  int* pk_rd           = (int*)(w + off);            off = align256(off + (size_t)E*4);

  const int nblk_rd = (8*n + 8191) / 8192;       // 49
  const int cnt4 = n*GD/4;                       // 1.6M
  const int ncastb = (cnt4 + 1023)/1024;         // 1563
  const int histb  = (E + 255)/256;              // 2344
  const int npadz  = (npad - n)*GD/2;            // pad uint32 count

  hipMemsetAsync(cnt_rd, 0, (size_t)8*n*4, stream);

  k_prep<<<128 + 256 + ncastb + 12 + histb, 256, 0, stream>>>(
      comp, basis, root, Bht, wk, wq, wv, wsk, bk, bq, bv, bs, B2t, Bb,
      (const float4*)x, (uint2*)xbf, cnt4,
      (uint32_t*)(xbf + (size_t)n*GD), npadz,
      edst, etype, cnt_rd, E, n);
  k_scanA<<<nblk_rd, 1024, 0, stream>>>(cnt_rd, off_rd, btot_rd, 8*n);
  k_scanB<<<nblk_rd, 1024, 0, stream>>>(btot_rd, off_rd, cur_rd, 8*n, E);
  k_scatter_rd<<<(E + 255)/256, 256, 0, stream>>>(esrc, edst, etype, cur_rd, pk_rd, E, n);
  k_agg<<<(npad + 3)/4, 256, 0, stream>>>(off_rd, pk_rd, (const uint32_t*)xbf, A2, n, npad);
  k_hqkv<<<npad/64, 256, 0, stream>>>(A2, xbf, Bht, B2t, bias1, Bb, kqv, skipb);
  k_edge2<<<(n + 3)/4, 256, 0, stream>>>(off_rd, pk_rd, kqv, skipb, out, n);
}

// Round 12
// 327.191 us; speedup vs baseline: 1.0358x; 1.0237x over previous
//
#include <hip/hip_runtime.h>
#include <stdint.h>

#define GD 128
#define H1 128
#define H2 128
#define NBASES 32
#define NREL 8
#define KA 1152   // logical K = 8*128 (relation means) + 128 (x | root)

typedef __attribute__((ext_vector_type(8))) short bf16x8;
typedef __attribute__((ext_vector_type(4))) float f32x4;

static inline size_t align256(size_t x){ return (x + 255) & ~(size_t)255; }

__device__ __forceinline__ float bf2f(uint32_t u16){
  union { uint32_t u; float f; } c; c.u = (u16 & 0xffffu) << 16; return c.f;
}
__device__ __forceinline__ unsigned short f2bf(float f){
  union { float f; uint32_t u; } c; c.f = f;
  uint32_t u = c.u;
  u += 0x7fffu + ((u >> 16) & 1u);   // RTNE (finite inputs)
  return (unsigned short)(u >> 16);
}
__device__ __forceinline__ uint32_t pkbf(float a, float b){
  union { float f; uint32_t u; } ca, cb; ca.f = a; cb.f = b;
  return __builtin_amdgcn_perm(cb.u + 0x8000u, ca.u + 0x8000u, 0x07060302u);
}

__device__ __forceinline__ void async_copy16(void* lds_dst, const void* gsrc){
  __builtin_amdgcn_global_load_lds(
      (const __attribute__((address_space(1))) uint32_t*)gsrc,
      (__attribute__((address_space(3))) uint32_t*)lds_dst, 16, 0, 0);
}

// ==== merged prep: Bht build (coalesced) | B2t build (log2e prescale) | x cast | xbf pad zero | hist ====
__global__ void k_prep(const float* __restrict__ comp, const float* __restrict__ basis,
                       const float* __restrict__ root, unsigned short* __restrict__ Bht,
                       const float* __restrict__ wk, const float* __restrict__ wq,
                       const float* __restrict__ wv, const float* __restrict__ wsk,
                       const float* __restrict__ bk, const float* __restrict__ bq,
                       const float* __restrict__ bv, const float* __restrict__ bs,
                       unsigned short* __restrict__ B2t, float* __restrict__ Bb,
                       const float4* __restrict__ x, uint2* __restrict__ xout, int cnt4,
                       uint32_t* __restrict__ xpadz, int npadz,
                       const int* __restrict__ edst, const int* __restrict__ etyp,
                       int* __restrict__ cnt, int E, int n){
  const float LOG2E = 1.4426950408889634f;
  int b = blockIdx.x, t = threadIdx.x;
  if (b < 128){
    // block = K-row i; lane = output col o (coalesced basis reads, 256B/wave segments)
    int i = b;
    int o = t & 127, rh = t >> 7;
    float bv[NBASES];
    #pragma unroll
    for (int bb = 0; bb < NBASES; ++bb)
      bv[bb] = basis[((size_t)bb*GD + i)*H1 + o];
    #pragma unroll
    for (int rr = 0; rr < 4; ++rr){
      int r = rh*4 + rr;
      float acc = 0.f;
      #pragma unroll
      for (int bb = 0; bb < NBASES; ++bb)
        acc += comp[r*NBASES + bb] * bv[bb];
      Bht[(size_t)o*KA + r*128 + i] = f2bf(acc);
    }
    if (rh == 1) Bht[(size_t)o*KA + 1024 + i] = f2bf(root[(size_t)i*H1 + o]);
  } else if (b < 128 + 256){
    int idx = (b - 128)*256 + t;         // < 65536 = 512*H1
    int c = idx / H1, k = idx % H1;
    const float* w = (c < 128) ? wk : (c < 256) ? wq : (c < 384) ? wv : wsk;
    float val = w[(size_t)k*H2 + (c & 127)];
    if (c < 256) val *= LOG2E;           // fold log2e into k,q so edge2 uses raw v_exp
    B2t[idx] = f2bf(val);
    if (idx < 512){
      const float* bia = (idx < 128) ? bk : (idx < 256) ? bq : (idx < 384) ? bv : bs;
      float bval = bia[idx & 127];
      if (idx < 256) bval *= LOG2E;
      Bb[idx] = bval;
    }
  } else {
    int cb = b - (128 + 256);
    int ncastb = (cnt4 + 1023) >> 10;
    if (cb < ncastb){
      int base = cb*1024 + t;
      #pragma unroll
      for (int u = 0; u < 4; ++u){
        int i = base + u*256;
        if (i < cnt4){
          float4 v = x[i];
          uint2 o; o.x = pkbf(v.x, v.y); o.y = pkbf(v.z, v.w);
          xout[i] = o;
        }
      }
    } else if (cb < ncastb + 12){
      int i = (cb - ncastb)*256 + t;
      if (i < npadz) xpadz[i] = 0u;      // zero xbf pad rows (hgemm root chunk reads them)
    } else {
      int e = (cb - ncastb - 12)*256 + t;
      if (e < E) atomicAdd(&cnt[etyp[e]*n + edst[e]], 1);
    }
  }
}

// ---- parallel scan, stage A ----
__global__ void k_scanA(const int* __restrict__ deg, int* __restrict__ off,
                        int* __restrict__ btot, int len){
  __shared__ int wsum[16];
  int t = threadIdx.x, lane = t & 63, w = t >> 6;
  int i0 = blockIdx.x*8192 + t*8;
  int v[8];
  if (i0 + 7 < len){
    int4 va = *(const int4*)(deg + i0);
    int4 vb = *(const int4*)(deg + i0 + 4);
    v[0]=va.x; v[1]=va.y; v[2]=va.z; v[3]=va.w;
    v[4]=vb.x; v[5]=vb.y; v[6]=vb.z; v[7]=vb.w;
  } else {
    #pragma unroll
    for (int u = 0; u < 8; ++u) v[u] = (i0+u < len) ? deg[i0+u] : 0;
  }
  int s[8]; s[0] = v[0];
  #pragma unroll
  for (int u = 1; u < 8; ++u) s[u] = s[u-1] + v[u];
  int x = s[7];
  #pragma unroll
  for (int d = 1; d < 64; d <<= 1){
    int u = __shfl_up(x, d, 64);
    if (lane >= d) x += u;
  }
  if (lane == 63) wsum[w] = x;
  __syncthreads();
  if (t < 16){
    int y = wsum[t];
    #pragma unroll
    for (int d = 1; d < 16; d <<= 1){
      int u = __shfl_up(y, d, 16);
      if (t >= d) y += u;
    }
    wsum[t] = y;
  }
  __syncthreads();
  int woff = (w > 0) ? wsum[w-1] : 0;
  int excl = woff + x - s[7];
  #pragma unroll
  for (int u = 0; u < 8; ++u)
    if (i0+u < len) off[i0+u] = excl + s[u] - v[u];
  if (t == 0) btot[blockIdx.x] = wsum[15];
}

// ---- scan stage B ----
__global__ void k_scanB(const int* __restrict__ btot, int* __restrict__ off,
                        int* __restrict__ cursor, int len, int sentinel){
  int t = threadIdx.x, bid = blockIdx.x;
  int add = 0;
  for (int j = 0; j < bid; ++j) add += btot[j];
  int i0 = bid*8192 + t*8;
  #pragma unroll
  for (int u = 0; u < 8; ++u){
    int i = i0 + u;
    if (i < len){ int val = off[i] + add; off[i] = val; cursor[i] = val; }
  }
  if (bid == 0 && t == 0) off[len] = sentinel;
}

// pk[pos] = src, (r,dst)-sorted
__global__ void k_scatter_rd(const int* __restrict__ src, const int* __restrict__ dst,
                             const int* __restrict__ typ, int* __restrict__ cursor,
                             int* __restrict__ pk, int E, int n){
  int e = blockIdx.x*blockDim.x + threadIdx.x;
  if (e >= E) return;
  int pos = atomicAdd(&cursor[typ[e]*n + dst[e]], 1);
  pk[pos] = src[e];
}

// ---- one wave per dst node: A2[d] = [mean_r(x_src) for r=0..7] (bf16, width 1024) ----
// merged-relation pipelined gather: batched 8 across relation boundaries,
// scalar-uniform flush when the (sorted) relation id changes. Zero barriers, max occupancy.
__global__ void k_agg(const int* __restrict__ off_rd, const int* __restrict__ pk_rd,
                      const uint32_t* __restrict__ x32, unsigned short* __restrict__ A2,
                      int n, int npad){
  int wid = blockIdx.x*(blockDim.x >> 6) + (threadIdx.x >> 6);
  int lane = threadIdx.x & 63;
  if (wid >= npad) return;
  uint32_t* arow = (uint32_t*)(A2 + (size_t)wid*1024);
  if (wid >= n){
    #pragma unroll
    for (int u = 0; u < 8; ++u) arow[u*64 + lane] = 0u;
    return;
  }
  int r8 = lane & 7;
  int o_r = off_rd[(size_t)r8*n + wid];
  int e_r = off_rd[(size_t)r8*n + wid + 1];
  int c_r = e_r - o_r;
  float ic_r = (c_r > 0) ? __builtin_amdgcn_rcpf((float)c_r) : 0.f;
  int c0_ = __builtin_amdgcn_readlane(c_r, 0), c1_ = __builtin_amdgcn_readlane(c_r, 1);
  int c2_ = __builtin_amdgcn_readlane(c_r, 2), c3_ = __builtin_amdgcn_readlane(c_r, 3);
  int c4_ = __builtin_amdgcn_readlane(c_r, 4), c5_ = __builtin_amdgcn_readlane(c_r, 5);
  int c6_ = __builtin_amdgcn_readlane(c_r, 6), c7_ = __builtin_amdgcn_readlane(c_r, 7);
  int o0_ = __builtin_amdgcn_readlane(o_r, 0), o1_ = __builtin_amdgcn_readlane(o_r, 1);
  int o2_ = __builtin_amdgcn_readlane(o_r, 2), o3_ = __builtin_amdgcn_readlane(o_r, 3);
  int o4_ = __builtin_amdgcn_readlane(o_r, 4), o5_ = __builtin_amdgcn_readlane(o_r, 5);
  int o6_ = __builtin_amdgcn_readlane(o_r, 6), o7_ = __builtin_amdgcn_readlane(o_r, 7);
  int p1 = c0_, p2 = p1 + c1_, p3 = p2 + c2_, p4 = p3 + c3_;
  int p5 = p4 + c4_, p6 = p5 + c5_, p7 = p6 + c6_, dg = p7 + c7_;

  int cr = 0;                 // relation currently being accumulated (edges are rel-sorted)
  float a0 = 0.f, a1 = 0.f;

#define FLUSH(RK)                                                               \
  {                                                                             \
    float ic = __int_as_float(__builtin_amdgcn_readlane(__float_as_int(ic_r), cr)); \
    arow[cr*64 + lane] = pkbf(a0*ic, a1*ic);                                    \
    for (int q = cr + 1; q < (RK); ++q) arow[q*64 + lane] = 0u;                 \
    cr = (RK); a0 = 0.f; a1 = 0.f;                                              \
  }

  for (int jb = 0; jb < dg; jb += 64){
    int i = jb + lane;
    int adj = o0_, rel = 0;
    adj = (i >= p1) ? (o1_ - p1) : adj;  rel += (i >= p1);
    adj = (i >= p2) ? (o2_ - p2) : adj;  rel += (i >= p2);
    adj = (i >= p3) ? (o3_ - p3) : adj;  rel += (i >= p3);
    adj = (i >= p4) ? (o4_ - p4) : adj;  rel += (i >= p4);
    adj = (i >= p5) ? (o5_ - p5) : adj;  rel += (i >= p5);
    adj = (i >= p6) ? (o6_ - p6) : adj;  rel += (i >= p6);
    adj = (i >= p7) ? (o7_ - p7) : adj;  rel += (i >= p7);
    int m = dg - jb; if (m > 64) m = 64;
    int pj = (lane < m) ? pk_rd[adj + i] : 0;
    int jj = 0;
    for (; jj + 8 <= m; jj += 8){
      uint32_t g[8];
      #pragma unroll
      for (int k = 0; k < 8; ++k){
        int sN = __builtin_amdgcn_readlane(pj, jj + k);
        g[k] = x32[(size_t)(uint32_t)sN*64 + lane];
      }
      #pragma unroll
      for (int k = 0; k < 8; ++k){
        int rk = __builtin_amdgcn_readlane(rel, jj + k);
        if (rk != cr) FLUSH(rk);
        a0 += bf2f(g[k]); a1 += bf2f(g[k] >> 16);
      }
    }
    for (; jj < m; jj += 4){             // padded batch-4 tail: keeps 4 loads in flight
      int lim = m - 1;
      uint32_t g[4];
      #pragma unroll
      for (int k = 0; k < 4; ++k){
        int tt = jj + k; if (tt > lim) tt = lim;
        int sN = __builtin_amdgcn_readlane(pj, tt);
        g[k] = x32[(size_t)(uint32_t)sN*64 + lane];
      }
      #pragma unroll
      for (int k = 0; k < 4; ++k){
        int tt = jj + k;
        if (tt < m){
          int rk = __builtin_amdgcn_readlane(rel, tt);
          if (rk != cr) FLUSH(rk);
          a0 += bf2f(g[k]); a1 += bf2f(g[k] >> 16);
        }
      }
    }
  }
  FLUSH(8)                               // write last accumulated rel + trailing zeros
#undef FLUSH
}

// ---- hgemm: h[npad,128] = [A2 | xbf] @ Bht^T + bias1 (bf16 out, LDS-transpose epilogue) ----
__launch_bounds__(256)
__global__ void k_hgemm(const unsigned short* __restrict__ A, const unsigned short* __restrict__ xb,
                        const unsigned short* __restrict__ Bt,
                        const float* __restrict__ bias1, unsigned short* __restrict__ h){
  __shared__ char lds[16896];            // staging uses [0,16384); epilogue 64*264
  int t = threadIdx.x, lane = t & 63, wave = t >> 6;
  int row0 = blockIdx.x * 128;
  int mrow = lane & 15, quad = lane >> 4;
  int wrow = (wave & 1) * 64, wcol = (wave >> 1) * 64;
  int s = (mrow >> 1) & 3;
  int colsw = (((t & 3) ^ ((t >> 3) & 3)) << 3);

  const unsigned short* Asrc = A  + (size_t)(row0 + (t >> 2))*1024 + colsw;
  const unsigned short* Xsrc = xb + (size_t)(row0 + (t >> 2))*GD   + colsw;
  const unsigned short* Bsrc = Bt + (size_t)(t >> 2)*KA + colsw;
  char* ldsw = lds + wave*1024;

  int aoff = (wrow + mrow)*64 + ((quad ^ s) << 4);
  int boff = 8192 + (wcol + mrow)*64 + ((quad ^ s) << 4);

  f32x4 acc[4][4];
  #pragma unroll
  for (int i = 0; i < 4; ++i)
    #pragma unroll
    for (int j = 0; j < 4; ++j) acc[i][j] = (f32x4){0.f,0.f,0.f,0.f};

  for (int kt = 0; kt < KA; kt += 32){
    const unsigned short* a0p = (kt < 1024) ? (Asrc + kt)
                                            : (Xsrc + (kt - 1024));
    const unsigned short* a1p = (kt < 1024) ? (Asrc + (size_t)64*1024 + kt)
                                            : (Xsrc + (size_t)64*GD + (kt - 1024));
    __syncthreads();
    async_copy16(ldsw,         a0p);
    async_copy16(ldsw + 4096,  a1p);
    async_copy16(ldsw + 8192,  Bsrc + kt);
    async_copy16(ldsw + 12288, Bsrc + (size_t)64*KA + kt);
    __syncthreads();
    bf16x8 af[4], bf[4];
    #pragma unroll
    for (int i = 0; i < 4; ++i) af[i] = *(const bf16x8*)(lds + aoff + i*1024);
    #pragma unroll
    for (int j = 0; j < 4; ++j) bf[j] = *(const bf16x8*)(lds + boff + j*1024);
    #pragma unroll
    for (int i = 0; i < 4; ++i)
      #pragma unroll
      for (int j = 0; j < 4; ++j)
        acc[i][j] = __builtin_amdgcn_mfma_f32_16x16x32_bf16(af[i], bf[j], acc[i][j], 0, 0, 0);
  }
  // epilogue: bias + bf16 -> LDS transpose -> coalesced 64B/lane row stores
  float bc[4];
  #pragma unroll
  for (int j = 0; j < 4; ++j) bc[j] = bias1[wcol + j*16 + mrow];
  #pragma unroll
  for (int p = 0; p < 2; ++p){
    __syncthreads();
    if ((wave & 1) == p){
      #pragma unroll
      for (int j = 0; j < 4; ++j){
        int col = wcol + j*16 + mrow;
        #pragma unroll
        for (int i = 0; i < 4; ++i)
          #pragma unroll
          for (int rg = 0; rg < 4; ++rg){
            int rl = i*16 + quad*4 + rg;
            *(unsigned short*)(lds + rl*264 + col*2) = f2bf(acc[i][j][rg] + bc[j]);
          }
      }
    }
    __syncthreads();
    uint32_t vv[16];
    #pragma unroll
    for (int u = 0; u < 8; ++u)
      *(uint2*)&vv[u*2] = *(const uint2*)(lds + lane*264 + wave*64 + u*8);
    unsigned short* gp = h + (size_t)(row0 + p*64 + lane)*H1 + wave*32;
    #pragma unroll
    for (int u = 0; u < 4; ++u)
      *(uint4*)(gp + u*8) = *(const uint4*)&vv[u*4];
  }
}

// ---- GEMM2 v2: y=0 -> k (transpose epilogue, kbuf); y=2 -> skip (transpose epilogue);
//      y=1 -> q-pass then v-pass, packed qv[row][ch] = q|v<<16, direct sector-complete stores.
__launch_bounds__(256)
__global__ void k_gemm2(const unsigned short* __restrict__ A, const unsigned short* __restrict__ Bt,
                        const float* __restrict__ Bb, unsigned short* __restrict__ kbuf,
                        uint32_t* __restrict__ qvbuf, unsigned short* __restrict__ skipb){
  __shared__ char lds[16896];
  int t = threadIdx.x, lane = t & 63, wave = t >> 6;
  int row0 = blockIdx.x * 128;
  int y = blockIdx.y;
  int mrow = lane & 15, quad = lane >> 4;
  int wrow = (wave & 1) * 64, wcol = (wave >> 1) * 64;
  int s = (mrow >> 1) & 3;
  int colsw = (((t & 3) ^ ((t >> 3) & 3)) << 3);

  const unsigned short* Asrc = A + (size_t)(row0 + (t >> 2))*H1 + colsw;
  char* ldsw = lds + wave*1024;

  int aoff = (wrow + mrow)*64 + ((quad ^ s) << 4);
  int boff = 8192 + (wcol + mrow)*64 + ((quad ^ s) << 4);

  f32x4 acc[4][4];
  int npass = (y == 1) ? 2 : 1;
  uint32_t qs[4][4][2];                  // q stash (bf16 pairs) for y==1

  for (int pass = 0; pass < npass; ++pass){
    int c0 = (y == 0) ? 0 : (y == 2) ? 3 : (1 + pass);
    const unsigned short* Bsrc = Bt + (size_t)(c0*128 + (t >> 2))*H1 + colsw;
    #pragma unroll
    for (int i = 0; i < 4; ++i)
      #pragma unroll
      for (int j = 0; j < 4; ++j) acc[i][j] = (f32x4){0.f,0.f,0.f,0.f};

    #pragma unroll
    for (int kt = 0; kt < H1; kt += 32){
      __syncthreads();
      async_copy16(ldsw,         Asrc + kt);
      async_copy16(ldsw + 4096,  Asrc + (size_t)64*H1 + kt);
      async_copy16(ldsw + 8192,  Bsrc + kt);
      async_copy16(ldsw + 12288, Bsrc + (size_t)64*H1 + kt);
      __syncthreads();
      bf16x8 af[4], bf[4];
      #pragma unroll
      for (int i = 0; i < 4; ++i) af[i] = *(const bf16x8*)(lds + aoff + i*1024);
      #pragma unroll
      for (int j = 0; j < 4; ++j) bf[j] = *(const bf16x8*)(lds + boff + j*1024);
      #pragma unroll
      for (int i = 0; i < 4; ++i)
        #pragma unroll
        for (int j = 0; j < 4; ++j)
          acc[i][j] = __builtin_amdgcn_mfma_f32_16x16x32_bf16(af[i], bf[j], acc[i][j], 0, 0, 0);
    }

    float bc[4];
    #pragma unroll
    for (int j = 0; j < 4; ++j) bc[j] = Bb[c0*128 + wcol + j*16 + mrow];

    if (y == 1){
      if (pass == 0){
        // stash q (bias applied) as bf16 pairs
        #pragma unroll
        for (int i = 0; i < 4; ++i)
          #pragma unroll
          for (int j = 0; j < 4; ++j){
            qs[i][j][0] = pkbf(acc[i][j][0] + bc[j], acc[i][j][1] + bc[j]);
            qs[i][j][1] = pkbf(acc[i][j][2] + bc[j], acc[i][j][3] + bc[j]);
          }
      } else {
        // pack q|v and store direct (sector-complete: 16 consecutive ch x 4B = 64B)
        #pragma unroll
        for (int j = 0; j < 4; ++j){
          int col = wcol + j*16 + mrow;
          #pragma unroll
          for (int i = 0; i < 4; ++i)
            #pragma unroll
            for (int rg = 0; rg < 4; ++rg){
              int row = row0 + wrow + i*16 + quad*4 + rg;
              uint32_t ql = (qs[i][j][rg >> 1] >> ((rg & 1)*16)) & 0xffffu;
              uint32_t pk = ql | ((uint32_t)f2bf(acc[i][j][rg] + bc[j]) << 16);
              qvbuf[(size_t)row*128 + col] = pk;
            }
        }
      }
    } else {
      unsigned short* dstb = (y == 0) ? kbuf : skipb;
      #pragma unroll
      for (int p = 0; p < 2; ++p){
        __syncthreads();
        if ((wave & 1) == p){
          #pragma unroll
          for (int j = 0; j < 4; ++j){
            int col = wcol + j*16 + mrow;
            #pragma unroll
            for (int i = 0; i < 4; ++i)
              #pragma unroll
              for (int rg = 0; rg < 4; ++rg){
                int rl = i*16 + quad*4 + rg;
                *(unsigned short*)(lds + rl*264 + col*2) = f2bf(acc[i][j][rg] + bc[j]);
              }
          }
        }
        __syncthreads();
        uint32_t vv[16];
        #pragma unroll
        for (int u = 0; u < 8; ++u)
          *(uint2*)&vv[u*2] = *(const uint2*)(lds + lane*264 + wave*64 + u*8);
        unsigned short* gp = dstb + (size_t)(row0 + p*64 + lane)*H1 + wave*32;
        #pragma unroll
        for (int u = 0; u < 4; ++u)
          *(uint4*)(gp + u*8) = *(const uint4*)&vv[u*4];
      }
    }
  }
}

// ---- one wave per dst node: out = sum_e sigmoid(k+q)*v + skip (pure write) ----
// kbuf[row][128] bf16; qvbuf[row][ch] = q_ch | v_ch<<16 (one uint2 gather per edge per lane);
// k,q prescaled by log2e: sigmoid = rcp(1+exp2(-(k+q)))
__global__ void k_edge2(const int* __restrict__ off_rd, const int* __restrict__ pk_rd,
                        const unsigned short* __restrict__ kbuf,
                        const uint32_t* __restrict__ qvbuf,
                        const unsigned short* __restrict__ skipb,
                        float* __restrict__ out, int n){
  int wid = blockIdx.x*(blockDim.x >> 6) + (threadIdx.x >> 6);
  int lane = threadIdx.x & 63;
  if (wid >= n) return;
  int r = lane & 7;
  int o_r = off_rd[(size_t)r*n + wid];
  int e_r = off_rd[(size_t)r*n + wid + 1];
  int c_r = e_r - o_r;
  int c0_ = __builtin_amdgcn_readlane(c_r, 0), c1_ = __builtin_amdgcn_readlane(c_r, 1);
  int c2_ = __builtin_amdgcn_readlane(c_r, 2), c3_ = __builtin_amdgcn_readlane(c_r, 3);
  int c4_ = __builtin_amdgcn_readlane(c_r, 4), c5_ = __builtin_amdgcn_readlane(c_r, 5);
  int c6_ = __builtin_amdgcn_readlane(c_r, 6), c7_ = __builtin_amdgcn_readlane(c_r, 7);
  int o0_ = __builtin_amdgcn_readlane(o_r, 0), o1_ = __builtin_amdgcn_readlane(o_r, 1);
  int o2_ = __builtin_amdgcn_readlane(o_r, 2), o3_ = __builtin_amdgcn_readlane(o_r, 3);
  int o4_ = __builtin_amdgcn_readlane(o_r, 4), o5_ = __builtin_amdgcn_readlane(o_r, 5);
  int o6_ = __builtin_amdgcn_readlane(o_r, 6), o7_ = __builtin_amdgcn_readlane(o_r, 7);
  int p1 = c0_, p2 = p1 + c1_, p3 = p2 + c2_, p4 = p3 + c3_;
  int p5 = p4 + c4_, p6 = p5 + c5_, p7 = p6 + c6_, dg = p7 + c7_;

  uint32_t ku = ((const uint32_t*)kbuf)[(size_t)wid*64 + lane];
  float k0 = bf2f(ku), k1 = bf2f(ku >> 16);
  float a0 = 0.f, a1 = 0.f;
  for (int jb = 0; jb < dg; jb += 64){
    int i = jb + lane;
    int adj = o0_;
    adj = (i >= p1) ? (o1_ - p1) : adj;
    adj = (i >= p2) ? (o2_ - p2) : adj;
    adj = (i >= p3) ? (o3_ - p3) : adj;
    adj = (i >= p4) ? (o4_ - p4) : adj;
    adj = (i >= p5) ? (o5_ - p5) : adj;
    adj = (i >= p6) ? (o6_ - p6) : adj;
    adj = (i >= p7) ? (o7_ - p7) : adj;
    int m = dg - jb; if (m > 64) m = 64;
    int pj = (lane < m) ? pk_rd[adj + i] : 0;
    int jj = 0;
    for (; jj + 8 <= m; jj += 8){
      uint2 g[8];
      #pragma unroll
      for (int k = 0; k < 8; ++k){
        int s = __builtin_amdgcn_readlane(pj, jj + k);
        g[k] = *(const uint2*)(qvbuf + (size_t)s*128 + lane*2);
      }
      #pragma unroll
      for (int k = 0; k < 8; ++k){
        float qq0 = bf2f(g[k].x), vv0 = bf2f(g[k].x >> 16);
        float qq1 = bf2f(g[k].y), vv1 = bf2f(g[k].y >> 16);
        float g0 = __builtin_amdgcn_rcpf(1.f + __builtin_amdgcn_exp2f(-(k0 + qq0)));
        float g1 = __builtin_amdgcn_rcpf(1.f + __builtin_amdgcn_exp2f(-(k1 + qq1)));
        a0 += g0*vv0; a1 += g1*vv1;
      }
    }
    for (; jj + 4 <= m; jj += 4){
      uint2 g[4];
      #pragma unroll
      for (int k = 0; k < 4; ++k){
        int s = __builtin_amdgcn_readlane(pj, jj + k);
        g[k] = *(const uint2*)(qvbuf + (size_t)s*128 + lane*2);
      }
      #pragma unroll
      for (int k = 0; k < 4; ++k){
        float qq0 = bf2f(g[k].x), vv0 = bf2f(g[k].x >> 16);
        float qq1 = bf2f(g[k].y), vv1 = bf2f(g[k].y >> 16);
        float g0 = __builtin_amdgcn_rcpf(1.f + __builtin_amdgcn_exp2f(-(k0 + qq0)));
        float g1 = __builtin_amdgcn_rcpf(1.f + __builtin_amdgcn_exp2f(-(k1 + qq1)));
        a0 += g0*vv0; a1 += g1*vv1;
      }
    }
    for (; jj < m; ++jj){
      int s = __builtin_amdgcn_readlane(pj, jj);
      uint2 g = *(const uint2*)(qvbuf + (size_t)s*128 + lane*2);
      float qq0 = bf2f(g.x), vv0 = bf2f(g.x >> 16);
      float qq1 = bf2f(g.y), vv1 = bf2f(g.y >> 16);
      float g0 = __builtin_amdgcn_rcpf(1.f + __builtin_amdgcn_exp2f(-(k0 + qq0)));
      float g1 = __builtin_amdgcn_rcpf(1.f + __builtin_amdgcn_exp2f(-(k1 + qq1)));
      a0 += g0*vv0; a1 += g1*vv1;
    }
  }
  uint32_t sk = ((const uint32_t*)skipb)[(size_t)wid*64 + lane];
  float2 cur; cur.x = a0 + bf2f(sk); cur.y = a1 + bf2f(sk >> 16);
  ((float2*)(out + (size_t)wid*H2))[lane] = cur;
}

extern "C" void kernel_launch(void* const* d_in, const int* in_sizes, int n_in,
                              void* d_out, int out_size, void* d_ws, size_t ws_size,
                              hipStream_t stream){
  const float* x     = (const float*)d_in[0];
  const int*   eidx  = (const int*)  d_in[1];
  const int*   etype = (const int*)  d_in[3];
  const float* basis = (const float*)d_in[4];
  const float* comp  = (const float*)d_in[5];
  const float* root  = (const float*)d_in[6];
  const float* bias1 = (const float*)d_in[7];
  const float* wk    = (const float*)d_in[8];
  const float* bk    = (const float*)d_in[9];
  const float* wq    = (const float*)d_in[10];
  const float* bq    = (const float*)d_in[11];
  const float* wv    = (const float*)d_in[12];
  const float* bv    = (const float*)d_in[13];
  const float* wsk   = (const float*)d_in[14];
  const float* bs    = (const float*)d_in[15];
  const int n = in_sizes[0] / GD;          // 50000
  const int E = in_sizes[3];               // 600000
  const int npad = (n + 127) & ~127;       // 50048
  const int* esrc = eidx;
  const int* edst = eidx + E;
  float* out = (float*)d_out;

  char* w = (char*)d_ws;
  size_t off = 0;
  unsigned short* xbf  = (unsigned short*)(w + off); off = align256(off + (size_t)npad*GD*2);
  unsigned short* A2   = (unsigned short*)(w + off); off = align256(off + (size_t)npad*1024*2);
  unsigned short* Bht  = (unsigned short*)(w + off); off = align256(off + (size_t)KA*H1*2);
  unsigned short* B2t  = (unsigned short*)(w + off); off = align256(off + (size_t)512*H1*2);
  float* Bb            = (float*)(w + off);          off = align256(off + 512*4);
  unsigned short* hbuf = (unsigned short*)(w + off); off = align256(off + (size_t)npad*H1*2);
  unsigned short* kbuf = (unsigned short*)(w + off); off = align256(off + (size_t)npad*H1*2);
  uint32_t* qvbuf      = (uint32_t*)(w + off);       off = align256(off + (size_t)npad*128*4);
  unsigned short* skipb= (unsigned short*)(w + off); off = align256(off + (size_t)npad*H2*2);
  int* cnt_rd          = (int*)(w + off);            off = align256(off + (size_t)(8*n+4)*4);
  int* off_rd          = (int*)(w + off);            off = align256(off + (size_t)(8*n+1)*4);
  int* cur_rd          = (int*)(w + off);            off = align256(off + (size_t)8*n*4);
  int* btot_rd         = (int*)(w + off);            off = align256(off + 64*4);
  int* pk_rd           = (int*)(w + off);            off = align256(off + (size_t)E*4);

  const int nblk_rd = (8*n + 8191) / 8192;       // 49
  const int cnt4 = n*GD/4;                       // 1.6M
  const int ncastb = (cnt4 + 1023)/1024;         // 1563
  const int histb  = (E + 255)/256;              // 2344
  const int npadz  = (npad - n)*GD/2;            // pad uint32 count

  hipMemsetAsync(cnt_rd, 0, (size_t)8*n*4, stream);

  k_prep<<<128 + 256 + ncastb + 12 + histb, 256, 0, stream>>>(
      comp, basis, root, Bht, wk, wq, wv, wsk, bk, bq, bv, bs, B2t, Bb,
      (const float4*)x, (uint2*)xbf, cnt4,
      (uint32_t*)(xbf + (size_t)n*GD), npadz,
      edst, etype, cnt_rd, E, n);
  k_scanA<<<nblk_rd, 1024, 0, stream>>>(cnt_rd, off_rd, btot_rd, 8*n);
  k_scanB<<<nblk_rd, 1024, 0, stream>>>(btot_rd, off_rd, cur_rd, 8*n, E);
  k_scatter_rd<<<(E + 255)/256, 256, 0, stream>>>(esrc, edst, etype, cur_rd, pk_rd, E, n);
  k_agg<<<(npad + 3)/4, 256, 0, stream>>>(off_rd, pk_rd, (const uint32_t*)xbf, A2, n, npad);
  k_hgemm<<<npad/128, 256, 0, stream>>>(A2, xbf, Bht, bias1, hbuf);
  k_gemm2<<<dim3(npad/128, 3), 256, 0, stream>>>(hbuf, B2t, Bb, kbuf, qvbuf, skipb);
  k_edge2<<<(n + 3)/4, 256, 0, stream>>>(off_rd, pk_rd, kbuf, qvbuf, skipb, out, n);
}